// Round 20
// baseline (190.904 us; speedup 1.0000x reference)
//
#include <hip/hip_runtime.h>

// Fused GNN forward for mynet_30039001268550 on gfx950 — round 20.
// = R19 (40 KiB LDS -> 4 blocks/CU) with the R19 bug fixed: the Ap nibble
// counts overlay the QPH scratch region, but its reads are UNSIGNED INT loads
// from memory later stored as UNSIGNED SHORT -> strict-aliasing TBAA lets the
// compiler sink the loads past the Q-GEMM stores (their first use is in
// gat_layer), reading Q-matrix bits as counts (absmax 0.18). Fix: volatile
// loads + asm memory barriers pin the two reads before the Q-GEMM scatter.
// Everything else identical to R19/R18: one wave = one graph, zero barriers,
// __shfl B-frag transpose, split-bf16 everywhere.

#define NGRAPH 4096
#define EDGES  (NGRAPH * 256)
#define NT     256
#define GPB    4
#define LOG2E  1.4426950408889634f

typedef __attribute__((ext_vector_type(8))) short bf16x8;
typedef __attribute__((ext_vector_type(4))) float f32x4;
typedef __attribute__((ext_vector_type(4))) int   i32x4;

__device__ __forceinline__ unsigned f2u(float x){ union{float f;unsigned u;}c;c.f=x;return c.u; }
__device__ __forceinline__ float u2f(unsigned u){ union{unsigned u;float f;}c;c.u=u;return c.f; }

__device__ __forceinline__ void split2(float x0, float x1, unsigned& dhi, unsigned& dlo){
    const unsigned u0 = f2u(x0), u1 = f2u(x1);
    dhi = (u0 >> 16) | (u1 & 0xffff0000u);
    const float l0 = x0 - u2f(u0 & 0xffff0000u);
    const float l1 = x1 - u2f(u1 & 0xffff0000u);
    dlo = (f2u(l0) >> 16) | (f2u(l1) & 0xffff0000u);
}

__device__ __forceinline__ f32x4 mfma16(i32x4 a, i32x4 b, f32x4 c){
    return __builtin_amdgcn_mfma_f32_16x16x32_bf16(
        __builtin_bit_cast(bf16x8, a), __builtin_bit_cast(bf16x8, b), c, 0, 0, 0);
}

// ws layout (bytes), total 94208 <= proven-safe 131072:
//   0     : Wt planes per layer l at l*16384: hi [64n][64k] bf16, lo +8192
//   65536 : esed shared tile per layer at 65536+l*4096: hi [16n][64k], lo +2048
//           rows 2h -> was'_h*log2e, 2h+1 -> wad'_h*log2e (l=3: head 0 dup)
//   81920 : QKV^T planes per mat at 81920+mat*4096: hi [32 i][32 m], lo +2048
template<int KSTEPS>
__device__ __forceinline__ void gat_layer(
    int lane, unsigned short* sw, float* esb, float* edb,
    unsigned apw0, unsigned apw1, const char* __restrict__ ws, int l,
    const float* __restrict__ b_g)
{
    const int n15 = lane & 15, q = lane >> 4;
    unsigned short* xaH = sw;
    unsigned short* xaL = sw + 2304;

    // ---- stage A: all 4 col-blocks of h (kept in regs) + esed, on MFMA ----
    f32x4 hC0[4], hC1[4];
    f32x4 eC0 = {0,0,0,0}, eC1 = {0,0,0,0};
#pragma unroll
    for (int nt = 0; nt < 4; ++nt){
        hC0[nt] = (f32x4){0,0,0,0};
        hC1[nt] = (f32x4){0,0,0,0};
    }
#pragma unroll
    for (int ks = 0; ks < KSTEPS; ++ks){
        const i32x4 a0h = *(const i32x4*)&xaH[n15*72 + ks*32 + q*8];
        const i32x4 a0l = *(const i32x4*)&xaL[n15*72 + ks*32 + q*8];
        const i32x4 a1h = *(const i32x4*)&xaH[(16+n15)*72 + ks*32 + q*8];
        const i32x4 a1l = *(const i32x4*)&xaL[(16+n15)*72 + ks*32 + q*8];

        const unsigned short* er = (const unsigned short*)(ws + 65536 + l*4096)
                                   + n15*64 + ks*32 + q*8;
        const i32x4 eh = *(const i32x4*)er;
        const i32x4 el = *(const i32x4*)(er + 1024);
        eC0 = mfma16(a0h, eh, eC0); eC0 = mfma16(a0h, el, eC0); eC0 = mfma16(a0l, eh, eC0);
        eC1 = mfma16(a1h, eh, eC1); eC1 = mfma16(a1h, el, eC1); eC1 = mfma16(a1l, eh, eC1);

#pragma unroll
        for (int nt = 0; nt < 4; ++nt){
            const unsigned short* wr = (const unsigned short*)(ws + l*16384)
                                       + (nt*16 + n15)*64 + ks*32 + q*8;
            const i32x4 bh = *(const i32x4*)wr;
            const i32x4 bl = *(const i32x4*)(wr + 4096);
            hC0[nt] = mfma16(a0h, bh, hC0[nt]);
            hC0[nt] = mfma16(a0h, bl, hC0[nt]);
            hC0[nt] = mfma16(a0l, bh, hC0[nt]);
            hC1[nt] = mfma16(a1h, bh, hC1[nt]);
            hC1[nt] = mfma16(a1h, bl, hC1[nt]);
            hC1[nt] = mfma16(a1l, bh, hC1[nt]);
        }
    }

    // ---- scatter es/ed, all 4 heads (C col 2h = es_h, 2h+1 = ed_h) ----
    if (n15 < 8){
        float* dst = (n15 & 1) ? edb : esb;
        const int h = n15 >> 1;
#pragma unroll
        for (int r = 0; r < 4; ++r){
            dst[h*32 + q*4 + r]      = eC0[r];
            dst[h*32 + 16 + q*4 + r] = eC1[r];
        }
    }

    // ---- per col-block: __shfl transpose -> B-frag, P-build, P@h, epilogue ----
#pragma unroll
    for (int nt = 0; nt < 4; ++nt){
        // B-frag (B[k=q*8+jj][n=n15] = h[node q*8+jj][ch nt*16+n15]) from the
        // stage-A C-layout via q-lane transpose: same column n15, src lane
        // (q&1)*32 + (jj>=4)*16 + n15, reg jj&3, tile select q&2.
        i32x4 bh, bl;
        {
            const int base = (q & 1)*32 + n15;
            float hv[8];
#pragma unroll
            for (int jj = 0; jj < 8; ++jj){
                const int src = base + ((jj >= 4) ? 16 : 0);
                const int r = jj & 3;
                const float v0 = __shfl(hC0[nt][r], src);
                const float v1 = __shfl(hC1[nt][r], src);
                hv[jj] = (q & 2) ? v1 : v0;
            }
            unsigned th, tl;
#pragma unroll
            for (int r2 = 0; r2 < 4; ++r2){
                split2(hv[2*r2], hv[2*r2+1], th, tl);
                bh[r2] = (int)th; bl[r2] = (int)tl;
            }
        }

        float pf0[8], pf1[8];
        {
            float es8[8];
            *(float4*)&es8[0] = *(const float4*)&esb[nt*32 + q*8];
            *(float4*)&es8[4] = *(const float4*)&esb[nt*32 + q*8 + 4];
            const float ed0 = edb[nt*32 + n15], ed1 = edb[nt*32 + 16 + n15];
            float ss0 = 0.f, ss1 = 0.f;
#pragma unroll
            for (int jj = 0; jj < 8; ++jj){
                const unsigned cnt0 = (apw0 >> (4*jj)) & 0xfu;
                const unsigned cnt1 = (apw1 >> (4*jj)) & 0xfu;
                float e0 = es8[jj] + ed0; e0 = fmaxf(e0, 0.2f*e0);  // lrelu, log2-dom
                float e1 = es8[jj] + ed1; e1 = fmaxf(e1, 0.2f*e1);
                const float p0 = (float)cnt0 * exp2f(e0);
                const float p1 = (float)cnt1 * exp2f(e1);
                pf0[jj] = p0; ss0 += p0;
                pf1[jj] = p1; ss1 += p1;
            }
            ss0 += __shfl_xor(ss0, 16); ss0 += __shfl_xor(ss0, 32);
            ss1 += __shfl_xor(ss1, 16); ss1 += __shfl_xor(ss1, 32);
            // inv overwrites ed slots for head nt (ed reads above complete)
            if (q == 0){
                edb[nt*32 + n15]      = 1.f/(ss0 + 1e-16f);
                edb[nt*32 + 16 + n15] = 1.f/(ss1 + 1e-16f);
            }
        }

        f32x4 o0 = {0,0,0,0}, o1 = {0,0,0,0};
        i32x4 ph, pl; unsigned th, tl;
#pragma unroll
        for (int r = 0; r < 4; ++r){
            split2(pf0[2*r], pf0[2*r+1], th, tl); ph[r] = (int)th; pl[r] = (int)tl;
        }
        o0 = mfma16(ph, bh, o0); o0 = mfma16(ph, bl, o0); o0 = mfma16(pl, bh, o0);
#pragma unroll
        for (int r = 0; r < 4; ++r){
            split2(pf1[2*r], pf1[2*r+1], th, tl); ph[r] = (int)th; pl[r] = (int)tl;
        }
        o1 = mfma16(ph, bh, o1); o1 = mfma16(ph, bl, o1); o1 = mfma16(pl, bh, o1);

        const float bv = __ldg(b_g + nt*16 + n15);
        const f32x4 iv0 = *(const f32x4*)&edb[nt*32 + q*4];
        const f32x4 iv1 = *(const f32x4*)&edb[nt*32 + 16 + q*4];
#pragma unroll
        for (int mt = 0; mt < 2; ++mt){
            const f32x4 ov = mt ? o1 : o0;
            const f32x4 iv = mt ? iv1 : iv0;
#pragma unroll
            for (int r = 0; r < 4; ++r){
                const int row = mt*16 + q*4 + r;
                float v = ov[r]*iv[r] + bv;
                v = fmaxf(v, 0.01f*v);
                const unsigned u = f2u(v);
                const float lo = v - u2f(u & 0xffff0000u);
                xaH[row*72 + nt*16 + n15] = (unsigned short)(u >> 16);
                xaL[row*72 + nt*16 + n15] = (unsigned short)(f2u(lo) >> 16);
            }
        }
    }
}

__global__ __launch_bounds__(NT) void gnn_fused(
    const float* __restrict__ x, const int* __restrict__ edge_index,
    const float* __restrict__ b1, const float* __restrict__ b2,
    const float* __restrict__ b3, const float* __restrict__ b4,
    const float* __restrict__ fcW, const float* __restrict__ fcb,
    const char* __restrict__ ws, float* __restrict__ out)
{
    __shared__ __align__(16) unsigned short sb[GPB][4608];  // per-wave xa + FE scratch
    __shared__ __align__(16) float esb_s[GPB][128];
    __shared__ __align__(16) float edb_s[GPB][128];
    // total: 36864 + 2048 + 2048 = 40960 B = 40 KiB -> 4 blocks/CU

    const int tid = threadIdx.x, lane = tid & 63, w = tid >> 6;
    const int g = blockIdx.x * GPB + w;
    const int n15 = lane & 15, q = lane >> 4;

    unsigned short* sw = sb[w];
    float* esb = esb_s[w];
    float* edb = edb_s[w];
    // Ap overlay: 160 nibble-count words on the QPH scratch region
    // (sw[1280..1600) shorts), dead until the Q-GEMM scatter.
    unsigned int* Ap = (unsigned int*)&sw[1280];

    // ---- zero Ap overlay (160 words), stage x^T, zero rows 10..15 ----
    Ap[lane] = 0u;
    Ap[64 + lane] = 0u;
    if (lane < 32) Ap[128 + lane] = 0u;
#pragma unroll
    for (int t = 0; t < 5; ++t){
        const int idx = lane + t*64;              // 0..319
        const int m = idx / 10, s = idx - 10*m;   // m = node, s = feat
        const float v = x[g*320 + idx];
        const unsigned u = f2u(v);
        const float lo = v - u2f(u & 0xffff0000u);
        sw[0   + s*40 + m] = (unsigned short)(u >> 16);
        sw[640 + s*40 + m] = (unsigned short)(f2u(lo) >> 16);
    }
#pragma unroll
    for (int t = 0; t < 3; ++t){                  // rows 10..15 feed QKV A-frag
        const int idx = lane + t*64;              // 0..191
        const int s = 10 + (idx >> 5), m = idx & 31;
        sw[0   + s*40 + m] = 0;
        sw[640 + s*40 + m] = 0;
    }

    // ---- edge counts (nibble atomics into overlay; max count 9 < 16),
    //      then read this lane's TWO words into registers. The reads are
    //      VOLATILE + asm memory barriers: the overlay is int-typed while the
    //      Q-GEMM later stores shorts there — TBAA would otherwise let the
    //      compiler sink these loads past those stores (the R19 bug). ----
    unsigned apw0, apw1;
    {
        const int* dstp = edge_index + EDGES + g*256;
        const int4 d4 = *(const int4*)(dstp + lane*4);
#pragma unroll
        for (int e = 0; e < 4; ++e){
            const int dv = (e==0) ? d4.x : (e==1) ? d4.y : (e==2) ? d4.z : d4.w;
            const int i = dv & 31, j = (lane*4 + e) >> 3;   // src = edge>>3
            atomicAdd(&Ap[i*5 + (j >> 3)], 1u << (4*(j & 7)));
        }
        if (lane < 32) atomicAdd(&Ap[lane*5 + (lane >> 3)], 1u << (4*(lane & 7)));
        __asm__ volatile("" ::: "memory");
        volatile const unsigned int* vAp = Ap;
        apw0 = vAp[n15*5 + q];          // nibbles j=q*8..q*8+7, row n15
        apw1 = vAp[(16+n15)*5 + q];     // row 16+n15
        __asm__ volatile("" ::: "memory");
    }

    // ---- attention front-end, fully wave-local (Q scatter reuses Ap region) ----
    {
        const i32x4 ah = *(const i32x4*)&sw[0   + n15*40 + q*8];   // XT A-frag
        const i32x4 al = *(const i32x4*)&sw[640 + n15*40 + q*8];

        // Q (-> 1280) and K (-> 2560) GEMMs, C scattered to [s][i] planes
#pragma unroll
        for (int mat = 0; mat < 2; ++mat){
            const unsigned short* wb = (const unsigned short*)(ws + 81920 + mat*4096);
            const int obase = 1280 + mat*1280;
#pragma unroll
            for (int nt = 0; nt < 2; ++nt){
                const i32x4 bh = *(const i32x4*)&wb[(nt*16+n15)*32 + q*8];
                const i32x4 bl = *(const i32x4*)&wb[1024 + (nt*16+n15)*32 + q*8];
                f32x4 C = {0,0,0,0};
                C = mfma16(ah, bh, C); C = mfma16(ah, bl, C); C = mfma16(al, bh, C);
                const int i = nt*16 + n15;
#pragma unroll
                for (int r = 0; r < 4; ++r){
                    const int s = q*4 + r;
                    const float v = C[r];
                    const unsigned u = f2u(v);
                    const float lo = v - u2f(u & 0xffff0000u);
                    sw[obase + s*40 + i]       = (unsigned short)(u >> 16);
                    sw[obase + 640 + s*40 + i] = (unsigned short)(f2u(lo) >> 16);
                }
            }
        }

        // V GEMM -> registers (written to LDS only after XT+Q are dead)
        f32x4 VC[2];
        {
            const unsigned short* wb = (const unsigned short*)(ws + 81920 + 2*4096);
#pragma unroll
            for (int nt = 0; nt < 2; ++nt){
                const i32x4 bh = *(const i32x4*)&wb[(nt*16+n15)*32 + q*8];
                const i32x4 bl = *(const i32x4*)&wb[1024 + (nt*16+n15)*32 + q*8];
                f32x4 C = {0,0,0,0};
                C = mfma16(ah, bh, C); C = mfma16(ah, bl, C); C = mfma16(al, bh, C);
                VC[nt] = C;
            }
        }

        // S = Q@K^T, in-register softmax, S' -> K region (K consumed)
        {
            const i32x4 qh = *(const i32x4*)&sw[1280 + n15*40 + q*8];
            const i32x4 ql = *(const i32x4*)&sw[1920 + n15*40 + q*8];
            const i32x4 kh = *(const i32x4*)&sw[2560 + n15*40 + q*8];
            const i32x4 kl = *(const i32x4*)&sw[3200 + n15*40 + q*8];
            f32x4 Sc = {0,0,0,0};
            Sc = mfma16(qh, kh, Sc); Sc = mfma16(qh, kl, Sc); Sc = mfma16(ql, kh, Sc);
            const bool valid = (n15 < 10);
#pragma unroll
            for (int r = 0; r < 4; ++r){
                float v = valid ? Sc[r] : -1e30f;
                float m = v;
                m = fmaxf(m, __shfl_xor(m, 1)); m = fmaxf(m, __shfl_xor(m, 2));
                m = fmaxf(m, __shfl_xor(m, 4)); m = fmaxf(m, __shfl_xor(m, 8));
                float p = valid ? exp2f((Sc[r] - m)*LOG2E) : 0.f;
                float s = p;
                s += __shfl_xor(s, 1); s += __shfl_xor(s, 2);
                s += __shfl_xor(s, 4); s += __shfl_xor(s, 8);
                const float sp = p / s;
                const int srow = q*4 + r;
                const unsigned u = f2u(sp);
                const float lo = sp - u2f(u & 0xffff0000u);
                sw[2560 + srow*40 + n15] = (unsigned short)(u >> 16);
                sw[3200 + srow*40 + n15] = (unsigned short)(f2u(lo) >> 16);
                sw[2560 + srow*40 + 16 + n15] = 0;   // zero k-tail t 16..31
                sw[3200 + srow*40 + 16 + n15] = 0;
            }
        }

        // V^T -> [0,2560) (XT and Q both dead now); zero t-tail 16..31
#pragma unroll
        for (int nt = 0; nt < 2; ++nt){
            const f32x4 cv = VC[nt];
            const int i = nt*16 + n15;
            unsigned h0, l0v, h1, l1v;
            split2(cv[0], cv[1], h0, l0v);
            split2(cv[2], cv[3], h1, l1v);
            *(uint2*)&sw[0    + i*40 + q*4] = make_uint2(h0, h1);
            *(uint2*)&sw[1280 + i*40 + q*4] = make_uint2(l0v, l1v);
        }
        {
            const int i2 = lane >> 1, half = lane & 1;
            const int b0 = i2*40 + 16 + half*8;
            *(unsigned long long*)&sw[b0]          = 0ull;
            *(unsigned long long*)&sw[b0 + 4]      = 0ull;
            *(unsigned long long*)&sw[1280 + b0]   = 0ull;
            *(unsigned long long*)&sw[1280 + b0+4] = 0ull;
        }

        // O = S'@V^T: BOTH tiles first (V^T fully read), then write xa
        f32x4 O[2];
        {
            const i32x4 sh = *(const i32x4*)&sw[2560 + n15*40 + q*8];
            const i32x4 sl = *(const i32x4*)&sw[3200 + n15*40 + q*8];
#pragma unroll
            for (int nt = 0; nt < 2; ++nt){
                const i32x4 vh = *(const i32x4*)&sw[0    + (nt*16+n15)*40 + q*8];
                const i32x4 vl = *(const i32x4*)&sw[1280 + (nt*16+n15)*40 + q*8];
                f32x4 C = {0,0,0,0};
                C = mfma16(sh, vh, C); C = mfma16(sh, vl, C); C = mfma16(sl, vh, C);
                O[nt] = C;
            }
        }
#pragma unroll
        for (int nt = 0; nt < 2; ++nt){
            const int i = nt*16 + n15;
#pragma unroll
            for (int r = 0; r < 4; ++r){
                const int s = q*4 + r;
                if (s < 10){
                    const float v = O[nt][r];
                    const unsigned u = f2u(v);
                    const float lo = v - u2f(u & 0xffff0000u);
                    sw[i*72 + s]        = (unsigned short)(u >> 16);
                    sw[2304 + i*72 + s] = (unsigned short)(f2u(lo) >> 16);
                }
            }
        }
        // zero xa cols 10..63 (both planes); lane -> (row, half)
#pragma unroll
        for (int p = 0; p < 2; ++p){
            unsigned short* rowp = sw + p*2304 + (lane >> 1)*72;
            if ((lane & 1) == 0){
                *(unsigned*)&rowp[10] = 0u;       // cols 10-11
#pragma unroll
                for (int c = 0; c < 6; ++c) *(unsigned long long*)&rowp[12 + 4*c] = 0ull;
            } else {
#pragma unroll
                for (int c = 0; c < 7; ++c) *(unsigned long long*)&rowp[36 + 4*c] = 0ull;
            }
        }
    }

    // ---- 4 GAT layers, no barriers ----
    gat_layer<1>(lane, sw, esb, edb, apw0, apw1, ws, 0, b1);
    gat_layer<2>(lane, sw, esb, edb, apw0, apw1, ws, 1, b2);
    gat_layer<2>(lane, sw, esb, edb, apw0, apw1, ws, 2, b3);
    gat_layer<2>(lane, sw, esb, edb, apw0, apw1, ws, 3, b4);

    // ---- mean pool (hi+lo) + FC(64->2) + softmax, per wave ----
    {
        float acc = 0.f;
#pragma unroll
        for (int n = 0; n < 32; ++n)
            acc += u2f(((unsigned)sw[n*72 + lane]) << 16)
                 + u2f(((unsigned)sw[2304 + n*72 + lane]) << 16);
        const float p = acc*(1.f/32.f);
        float c0 = p*__ldg(fcW + 2*lane);
        float c1 = p*__ldg(fcW + 2*lane + 1);
#pragma unroll
        for (int off = 32; off > 0; off >>= 1){
            c0 += __shfl_down(c0, off);
            c1 += __shfl_down(c1, off);
        }
        if (lane == 0){
            const float l0 = c0 + __ldg(fcb), l1 = c1 + __ldg(fcb + 1);
            const float m = fmaxf(l0, l1);
            const float e0 = __expf(l0 - m), e1 = __expf(l1 - m);
            const float inv = 1.f/(e0 + e1);
            out[2*g] = l0;
            out[2*g + 1] = l1;
            out[2*NGRAPH + 2*g] = e0*inv;
            out[2*NGRAPH + 2*g + 1] = e1*inv;
        }
    }
}

// prep: split-bf16 W^T planes, shared esed tiles, and QKV^T planes into d_ws.
__global__ void prep(
    const float* __restrict__ W1, const float* __restrict__ W2,
    const float* __restrict__ W3, const float* __restrict__ W4,
    const float* __restrict__ a1s, const float* __restrict__ a1d,
    const float* __restrict__ a2s, const float* __restrict__ a2d,
    const float* __restrict__ a3s, const float* __restrict__ a3d,
    const float* __restrict__ a4s, const float* __restrict__ a4d,
    const float* __restrict__ Wq, const float* __restrict__ Wk,
    const float* __restrict__ Wv,
    char* __restrict__ ws)
{
    const int b = blockIdx.x, tid = threadIdx.x;
    const float* Wl[4] = {W1, W2, W3, W4};
    const int Kl[4] = {10, 64, 64, 64};
    if (b < 32){
        const int l = b >> 3;
        const float* W = Wl[l];
        const int K = Kl[l];
        unsigned short* hi = (unsigned short*)(ws + l*16384);
        unsigned short* lo = hi + 4096;
        const int base = (b & 7)*512;
        for (int idx = base + tid; idx < base + 512; idx += NT){
            const int n = idx >> 6, k = idx & 63;
            const float v = (k < K) ? __ldg(W + k*64 + n) : 0.f;
            const unsigned u = f2u(v);
            const float lof = v - u2f(u & 0xffff0000u);
            hi[idx] = (unsigned short)(u >> 16);
            lo[idx] = (unsigned short)(f2u(lof) >> 16);
        }
    } else if (b < 36){
        const int l = b - 32;
        const float* W = Wl[l];
        const int K = Kl[l];
        const float* asp[4] = {a1s, a2s, a3s, a4s};
        const float* adp[4] = {a1d, a2d, a3d, a4d};
        const int C = (l < 3) ? 16 : 64;
        unsigned short* basep = (unsigned short*)(ws + 65536 + l*4096);
        for (int idx = tid; idx < 1024; idx += NT){
            const int n = idx >> 6, k = idx & 63;   // row n: 2h=was'_h, 2h+1=wad'_h
            float val = 0.f;
            if (n < 8 && k < K){
                const int hh = (l < 3) ? (n >> 1) : 0;
                const float* av = (n & 1) ? adp[l] : asp[l];
                float s = 0.f;
                for (int c = 0; c < C; ++c)
                    s += __ldg(W + k*64 + hh*C + c) * __ldg(av + hh*C + c);
                val = s * LOG2E;
            }
            const unsigned u = f2u(val);
            const float lof = val - u2f(u & 0xffff0000u);
            basep[idx]        = (unsigned short)(u >> 16);
            basep[1024 + idx] = (unsigned short)(f2u(lof) >> 16);
        }
    } else {
        const int mat = b - 36;
        const float* W = (mat == 0) ? Wq : ((mat == 1) ? Wk : Wv);
        unsigned short* hi = (unsigned short*)(ws + 81920 + mat*4096);
        unsigned short* lo = hi + 1024;
        for (int idx = tid; idx < 1024; idx += NT){
            const int i = idx >> 5, m = idx & 31;
            const float v = __ldg(W + m*32 + i);
            const unsigned u = f2u(v);
            const float lof = v - u2f(u & 0xffff0000u);
            hi[idx] = (unsigned short)(u >> 16);
            lo[idx] = (unsigned short)(f2u(lof) >> 16);
        }
    }
}

extern "C" void kernel_launch(void* const* d_in, const int* in_sizes, int n_in,
                              void* d_out, int out_size, void* d_ws, size_t ws_size,
                              hipStream_t stream) {
    (void)in_sizes; (void)n_in; (void)ws_size; (void)out_size;
    prep<<<39, NT, 0, stream>>>(
        (const float*)d_in[6], (const float*)d_in[10], (const float*)d_in[14], (const float*)d_in[18],
        (const float*)d_in[7], (const float*)d_in[8],
        (const float*)d_in[11], (const float*)d_in[12],
        (const float*)d_in[15], (const float*)d_in[16],
        (const float*)d_in[19], (const float*)d_in[20],
        (const float*)d_in[3], (const float*)d_in[4], (const float*)d_in[5],
        (char*)d_ws);
    gnn_fused<<<NGRAPH / GPB, NT, 0, stream>>>(
        (const float*)d_in[0], (const int*)d_in[1],
        (const float*)d_in[9], (const float*)d_in[13], (const float*)d_in[17], (const float*)d_in[21],
        (const float*)d_in[22], (const float*)d_in[23],
        (const char*)d_ws, (float*)d_out);
}

// Round 21
// 186.580 us; speedup vs baseline: 1.0232x; 1.0232x over previous
//
#include <hip/hip_runtime.h>

// Fused GNN forward for mynet_30039001268550 on gfx950 — round 21.
// EXACT REVERT TO R18 (best verified: 79.8 us/dispatch, absmax 3.9e-3).
// One wave = one graph, 4 graphs/block, ZERO __syncthreads; all GEMMs on
// MFMA 16x16x32_bf16 with split-bf16 (hi/lo truncation) operands; es/ed
// reassociated onto the MFMA via prepped esed tiles; stage-B B-frag built by
// an in-register q-lane transpose via __shfl; dedicated per-wave Ap nibble
// counts (R19/R20's overlay experiment regressed: TBAA hazard needed a
// volatile pin whose scheduling cost exceeded the occupancy gain).
// History: 243 (R1 fp32 LDS) -> 92 (R12 MFMA+fixes) -> 82 (R17 zero-barrier)
// -> 79.8 (R18). R6/R14/R15/R19/R20 showed occupancy/stores/barrier-count
// tweaks neutral-or-negative: this structure's plateau is ~80 us.

#define NGRAPH 4096
#define EDGES  (NGRAPH * 256)
#define NT     256
#define GPB    4
#define LOG2E  1.4426950408889634f

typedef __attribute__((ext_vector_type(8))) short bf16x8;
typedef __attribute__((ext_vector_type(4))) float f32x4;
typedef __attribute__((ext_vector_type(4))) int   i32x4;

__device__ __forceinline__ unsigned f2u(float x){ union{float f;unsigned u;}c;c.f=x;return c.u; }
__device__ __forceinline__ float u2f(unsigned u){ union{unsigned u;float f;}c;c.u=u;return c.f; }

__device__ __forceinline__ void split2(float x0, float x1, unsigned& dhi, unsigned& dlo){
    const unsigned u0 = f2u(x0), u1 = f2u(x1);
    dhi = (u0 >> 16) | (u1 & 0xffff0000u);
    const float l0 = x0 - u2f(u0 & 0xffff0000u);
    const float l1 = x1 - u2f(u1 & 0xffff0000u);
    dlo = (f2u(l0) >> 16) | (f2u(l1) & 0xffff0000u);
}

__device__ __forceinline__ f32x4 mfma16(i32x4 a, i32x4 b, f32x4 c){
    return __builtin_amdgcn_mfma_f32_16x16x32_bf16(
        __builtin_bit_cast(bf16x8, a), __builtin_bit_cast(bf16x8, b), c, 0, 0, 0);
}

// ws layout (bytes), total 94208 <= proven-safe 131072:
//   0     : Wt planes per layer l at l*16384: hi [64n][64k] bf16, lo +8192
//   65536 : esed shared tile per layer at 65536+l*4096: hi [16n][64k], lo +2048
//           rows 2h -> was'_h*log2e, 2h+1 -> wad'_h*log2e (l=3: head 0 dup)
//   81920 : QKV^T planes per mat at 81920+mat*4096: hi [32 i][32 m], lo +2048
template<int KSTEPS>
__device__ __forceinline__ void gat_layer(
    int lane, unsigned short* sw, float* esb, float* edb,
    const unsigned int* Ap, const char* __restrict__ ws, int l,
    const float* __restrict__ b_g)
{
    const int n15 = lane & 15, q = lane >> 4;
    unsigned short* xaH = sw;
    unsigned short* xaL = sw + 2304;

    // ---- stage A: all 4 col-blocks of h (kept in regs) + esed, on MFMA ----
    f32x4 hC0[4], hC1[4];
    f32x4 eC0 = {0,0,0,0}, eC1 = {0,0,0,0};
#pragma unroll
    for (int nt = 0; nt < 4; ++nt){
        hC0[nt] = (f32x4){0,0,0,0};
        hC1[nt] = (f32x4){0,0,0,0};
    }
#pragma unroll
    for (int ks = 0; ks < KSTEPS; ++ks){
        const i32x4 a0h = *(const i32x4*)&xaH[n15*72 + ks*32 + q*8];
        const i32x4 a0l = *(const i32x4*)&xaL[n15*72 + ks*32 + q*8];
        const i32x4 a1h = *(const i32x4*)&xaH[(16+n15)*72 + ks*32 + q*8];
        const i32x4 a1l = *(const i32x4*)&xaL[(16+n15)*72 + ks*32 + q*8];

        const unsigned short* er = (const unsigned short*)(ws + 65536 + l*4096)
                                   + n15*64 + ks*32 + q*8;
        const i32x4 eh = *(const i32x4*)er;
        const i32x4 el = *(const i32x4*)(er + 1024);
        eC0 = mfma16(a0h, eh, eC0); eC0 = mfma16(a0h, el, eC0); eC0 = mfma16(a0l, eh, eC0);
        eC1 = mfma16(a1h, eh, eC1); eC1 = mfma16(a1h, el, eC1); eC1 = mfma16(a1l, eh, eC1);

#pragma unroll
        for (int nt = 0; nt < 4; ++nt){
            const unsigned short* wr = (const unsigned short*)(ws + l*16384)
                                       + (nt*16 + n15)*64 + ks*32 + q*8;
            const i32x4 bh = *(const i32x4*)wr;
            const i32x4 bl = *(const i32x4*)(wr + 4096);
            hC0[nt] = mfma16(a0h, bh, hC0[nt]);
            hC0[nt] = mfma16(a0h, bl, hC0[nt]);
            hC0[nt] = mfma16(a0l, bh, hC0[nt]);
            hC1[nt] = mfma16(a1h, bh, hC1[nt]);
            hC1[nt] = mfma16(a1h, bl, hC1[nt]);
            hC1[nt] = mfma16(a1l, bh, hC1[nt]);
        }
    }

    // ---- scatter es/ed, all 4 heads (C col 2h = es_h, 2h+1 = ed_h) ----
    if (n15 < 8){
        float* dst = (n15 & 1) ? edb : esb;
        const int h = n15 >> 1;
#pragma unroll
        for (int r = 0; r < 4; ++r){
            dst[h*32 + q*4 + r]      = eC0[r];
            dst[h*32 + 16 + q*4 + r] = eC1[r];
        }
    }

    // ---- per col-block: __shfl transpose -> B-frag, P-build, P@h, epilogue ----
#pragma unroll
    for (int nt = 0; nt < 4; ++nt){
        // B-frag (B[k=q*8+jj][n=n15] = h[node q*8+jj][ch nt*16+n15]) from the
        // stage-A C-layout via q-lane transpose: same column n15, src lane
        // (q&1)*32 + (jj>=4)*16 + n15, reg jj&3, tile select q&2.
        i32x4 bh, bl;
        {
            const int base = (q & 1)*32 + n15;
            float hv[8];
#pragma unroll
            for (int jj = 0; jj < 8; ++jj){
                const int src = base + ((jj >= 4) ? 16 : 0);
                const int r = jj & 3;
                const float v0 = __shfl(hC0[nt][r], src);
                const float v1 = __shfl(hC1[nt][r], src);
                hv[jj] = (q & 2) ? v1 : v0;
            }
            unsigned th, tl;
#pragma unroll
            for (int r2 = 0; r2 < 4; ++r2){
                split2(hv[2*r2], hv[2*r2+1], th, tl);
                bh[r2] = (int)th; bl[r2] = (int)tl;
            }
        }

        float pf0[8], pf1[8];
        {
            float es8[8];
            *(float4*)&es8[0] = *(const float4*)&esb[nt*32 + q*8];
            *(float4*)&es8[4] = *(const float4*)&esb[nt*32 + q*8 + 4];
            const float ed0 = edb[nt*32 + n15], ed1 = edb[nt*32 + 16 + n15];
            const unsigned c0w = Ap[n15*5 + q];        // nibbles j=q*8..q*8+7
            const unsigned c1w = Ap[(16+n15)*5 + q];
            float ss0 = 0.f, ss1 = 0.f;
#pragma unroll
            for (int jj = 0; jj < 8; ++jj){
                const unsigned cnt0 = (c0w >> (4*jj)) & 0xfu;
                const unsigned cnt1 = (c1w >> (4*jj)) & 0xfu;
                float e0 = es8[jj] + ed0; e0 = fmaxf(e0, 0.2f*e0);  // lrelu, log2-dom
                float e1 = es8[jj] + ed1; e1 = fmaxf(e1, 0.2f*e1);
                const float p0 = (float)cnt0 * exp2f(e0);
                const float p1 = (float)cnt1 * exp2f(e1);
                pf0[jj] = p0; ss0 += p0;
                pf1[jj] = p1; ss1 += p1;
            }
            ss0 += __shfl_xor(ss0, 16); ss0 += __shfl_xor(ss0, 32);
            ss1 += __shfl_xor(ss1, 16); ss1 += __shfl_xor(ss1, 32);
            // inv overwrites ed slots for head nt (ed reads above complete)
            if (q == 0){
                edb[nt*32 + n15]      = 1.f/(ss0 + 1e-16f);
                edb[nt*32 + 16 + n15] = 1.f/(ss1 + 1e-16f);
            }
        }

        f32x4 o0 = {0,0,0,0}, o1 = {0,0,0,0};
        i32x4 ph, pl; unsigned th, tl;
#pragma unroll
        for (int r = 0; r < 4; ++r){
            split2(pf0[2*r], pf0[2*r+1], th, tl); ph[r] = (int)th; pl[r] = (int)tl;
        }
        o0 = mfma16(ph, bh, o0); o0 = mfma16(ph, bl, o0); o0 = mfma16(pl, bh, o0);
#pragma unroll
        for (int r = 0; r < 4; ++r){
            split2(pf1[2*r], pf1[2*r+1], th, tl); ph[r] = (int)th; pl[r] = (int)tl;
        }
        o1 = mfma16(ph, bh, o1); o1 = mfma16(ph, bl, o1); o1 = mfma16(pl, bh, o1);

        const float bv = __ldg(b_g + nt*16 + n15);
        const f32x4 iv0 = *(const f32x4*)&edb[nt*32 + q*4];
        const f32x4 iv1 = *(const f32x4*)&edb[nt*32 + 16 + q*4];
#pragma unroll
        for (int mt = 0; mt < 2; ++mt){
            const f32x4 ov = mt ? o1 : o0;
            const f32x4 iv = mt ? iv1 : iv0;
#pragma unroll
            for (int r = 0; r < 4; ++r){
                const int row = mt*16 + q*4 + r;
                float v = ov[r]*iv[r] + bv;
                v = fmaxf(v, 0.01f*v);
                const unsigned u = f2u(v);
                const float lo = v - u2f(u & 0xffff0000u);
                xaH[row*72 + nt*16 + n15] = (unsigned short)(u >> 16);
                xaL[row*72 + nt*16 + n15] = (unsigned short)(f2u(lo) >> 16);
            }
        }
    }
}

__global__ __launch_bounds__(NT) void gnn_fused(
    const float* __restrict__ x, const int* __restrict__ edge_index,
    const float* __restrict__ b1, const float* __restrict__ b2,
    const float* __restrict__ b3, const float* __restrict__ b4,
    const float* __restrict__ fcW, const float* __restrict__ fcb,
    const char* __restrict__ ws, float* __restrict__ out)
{
    __shared__ __align__(16) unsigned short sb[GPB][5888];
    __shared__ __align__(16) float esb_s[GPB][128];
    __shared__ __align__(16) float edb_s[GPB][128];
    __shared__ unsigned int Ap_s[GPB][160];   // nibble counts: 32 rows x 5 words

    const int tid = threadIdx.x, lane = tid & 63, w = tid >> 6;
    const int g = blockIdx.x * GPB + w;
    const int n15 = lane & 15, q = lane >> 4;

    unsigned short* sw = sb[w];
    float* esb = esb_s[w];
    float* edb = edb_s[w];
    unsigned int* Ap = Ap_s[w];

    // ---- zero Ap (160 words), stage x^T (split-bf16), zero rows 10..15 ----
    Ap[lane] = 0u;
    Ap[64 + lane] = 0u;
    if (lane < 32) Ap[128 + lane] = 0u;
#pragma unroll
    for (int t = 0; t < 5; ++t){
        const int idx = lane + t*64;              // 0..319
        const int m = idx / 10, s = idx - 10*m;   // m = node, s = feat
        const float v = x[g*320 + idx];
        const unsigned u = f2u(v);
        const float lo = v - u2f(u & 0xffff0000u);
        sw[0   + s*40 + m] = (unsigned short)(u >> 16);
        sw[640 + s*40 + m] = (unsigned short)(f2u(lo) >> 16);
    }
#pragma unroll
    for (int t = 0; t < 3; ++t){                  // rows 10..15 feed QKV A-frag
        const int idx = lane + t*64;              // 0..191
        const int s = 10 + (idx >> 5), m = idx & 31;
        sw[0   + s*40 + m] = 0;
        sw[640 + s*40 + m] = 0;
    }

    // ---- edge counts (wave-private nibble atomics; max count 9 < 16) ----
    {
        const int* dstp = edge_index + EDGES + g*256;
        const int4 d4 = *(const int4*)(dstp + lane*4);
#pragma unroll
        for (int e = 0; e < 4; ++e){
            const int dv = (e==0) ? d4.x : (e==1) ? d4.y : (e==2) ? d4.z : d4.w;
            const int i = dv & 31, j = (lane*4 + e) >> 3;   // src = edge>>3
            atomicAdd(&Ap[i*5 + (j >> 3)], 1u << (4*(j & 7)));
        }
        if (lane < 32) atomicAdd(&Ap[lane*5 + (lane >> 3)], 1u << (4*(lane & 7)));
    }

    // ---- attention front-end, fully wave-local ----
    {
        const i32x4 ah = *(const i32x4*)&sw[0   + n15*40 + q*8];   // XT A-frag
        const i32x4 al = *(const i32x4*)&sw[640 + n15*40 + q*8];

        // Q (-> 1280) and K (-> 2560) GEMMs, C scattered to [s][i] planes
#pragma unroll
        for (int mat = 0; mat < 2; ++mat){
            const unsigned short* wb = (const unsigned short*)(ws + 81920 + mat*4096);
            const int obase = 1280 + mat*1280;
#pragma unroll
            for (int nt = 0; nt < 2; ++nt){
                const i32x4 bh = *(const i32x4*)&wb[(nt*16+n15)*32 + q*8];
                const i32x4 bl = *(const i32x4*)&wb[1024 + (nt*16+n15)*32 + q*8];
                f32x4 C = {0,0,0,0};
                C = mfma16(ah, bh, C); C = mfma16(ah, bl, C); C = mfma16(al, bh, C);
                const int i = nt*16 + n15;
#pragma unroll
                for (int r = 0; r < 4; ++r){
                    const int s = q*4 + r;
                    const float v = C[r];
                    const unsigned u = f2u(v);
                    const float lo = v - u2f(u & 0xffff0000u);
                    sw[obase + s*40 + i]       = (unsigned short)(u >> 16);
                    sw[obase + 640 + s*40 + i] = (unsigned short)(f2u(lo) >> 16);
                }
            }
        }

        // V GEMM -> registers (written to LDS only after XT+Q are dead)
        f32x4 VC[2];
        {
            const unsigned short* wb = (const unsigned short*)(ws + 81920 + 2*4096);
#pragma unroll
            for (int nt = 0; nt < 2; ++nt){
                const i32x4 bh = *(const i32x4*)&wb[(nt*16+n15)*32 + q*8];
                const i32x4 bl = *(const i32x4*)&wb[1024 + (nt*16+n15)*32 + q*8];
                f32x4 C = {0,0,0,0};
                C = mfma16(ah, bh, C); C = mfma16(ah, bl, C); C = mfma16(al, bh, C);
                VC[nt] = C;
            }
        }

        // S = Q@K^T, in-register softmax, S' -> K region (K consumed)
        {
            const i32x4 qh = *(const i32x4*)&sw[1280 + n15*40 + q*8];
            const i32x4 ql = *(const i32x4*)&sw[1920 + n15*40 + q*8];
            const i32x4 kh = *(const i32x4*)&sw[2560 + n15*40 + q*8];
            const i32x4 kl = *(const i32x4*)&sw[3200 + n15*40 + q*8];
            f32x4 Sc = {0,0,0,0};
            Sc = mfma16(qh, kh, Sc); Sc = mfma16(qh, kl, Sc); Sc = mfma16(ql, kh, Sc);
            const bool valid = (n15 < 10);
#pragma unroll
            for (int r = 0; r < 4; ++r){
                float v = valid ? Sc[r] : -1e30f;
                float m = v;
                m = fmaxf(m, __shfl_xor(m, 1)); m = fmaxf(m, __shfl_xor(m, 2));
                m = fmaxf(m, __shfl_xor(m, 4)); m = fmaxf(m, __shfl_xor(m, 8));
                float p = valid ? exp2f((Sc[r] - m)*LOG2E) : 0.f;
                float s = p;
                s += __shfl_xor(s, 1); s += __shfl_xor(s, 2);
                s += __shfl_xor(s, 4); s += __shfl_xor(s, 8);
                const float sp = p / s;
                const int srow = q*4 + r;
                const unsigned u = f2u(sp);
                const float lo = sp - u2f(u & 0xffff0000u);
                sw[2560 + srow*40 + n15] = (unsigned short)(u >> 16);
                sw[3200 + srow*40 + n15] = (unsigned short)(f2u(lo) >> 16);
                sw[2560 + srow*40 + 16 + n15] = 0;   // zero k-tail t 16..31
                sw[3200 + srow*40 + 16 + n15] = 0;
            }
        }

        // V^T -> [0,2560) (XT and Q both dead now); zero t-tail 16..31
#pragma unroll
        for (int nt = 0; nt < 2; ++nt){
            const f32x4 cv = VC[nt];
            const int i = nt*16 + n15;
            unsigned h0, l0v, h1, l1v;
            split2(cv[0], cv[1], h0, l0v);
            split2(cv[2], cv[3], h1, l1v);
            *(uint2*)&sw[0    + i*40 + q*4] = make_uint2(h0, h1);
            *(uint2*)&sw[1280 + i*40 + q*4] = make_uint2(l0v, l1v);
        }
        {
            const int i2 = lane >> 1, half = lane & 1;
            const int b0 = i2*40 + 16 + half*8;
            *(unsigned long long*)&sw[b0]          = 0ull;
            *(unsigned long long*)&sw[b0 + 4]      = 0ull;
            *(unsigned long long*)&sw[1280 + b0]   = 0ull;
            *(unsigned long long*)&sw[1280 + b0+4] = 0ull;
        }

        // O = S'@V^T: BOTH tiles first (V^T fully read), then write xa
        f32x4 O[2];
        {
            const i32x4 sh = *(const i32x4*)&sw[2560 + n15*40 + q*8];
            const i32x4 sl = *(const i32x4*)&sw[3200 + n15*40 + q*8];
#pragma unroll
            for (int nt = 0; nt < 2; ++nt){
                const i32x4 vh = *(const i32x4*)&sw[0    + (nt*16+n15)*40 + q*8];
                const i32x4 vl = *(const i32x4*)&sw[1280 + (nt*16+n15)*40 + q*8];
                f32x4 C = {0,0,0,0};
                C = mfma16(sh, vh, C); C = mfma16(sh, vl, C); C = mfma16(sl, vh, C);
                O[nt] = C;
            }
        }
#pragma unroll
        for (int nt = 0; nt < 2; ++nt){
            const int i = nt*16 + n15;
#pragma unroll
            for (int r = 0; r < 4; ++r){
                const int s = q*4 + r;
                if (s < 10){
                    const float v = O[nt][r];
                    const unsigned u = f2u(v);
                    const float lo = v - u2f(u & 0xffff0000u);
                    sw[i*72 + s]        = (unsigned short)(u >> 16);
                    sw[2304 + i*72 + s] = (unsigned short)(f2u(lo) >> 16);
                }
            }
        }
        // zero xa cols 10..63 (both planes); lane -> (row, half)
#pragma unroll
        for (int p = 0; p < 2; ++p){
            unsigned short* rowp = sw + p*2304 + (lane >> 1)*72;
            if ((lane & 1) == 0){
                *(unsigned*)&rowp[10] = 0u;       // cols 10-11
#pragma unroll
                for (int c = 0; c < 6; ++c) *(unsigned long long*)&rowp[12 + 4*c] = 0ull;
            } else {
#pragma unroll
                for (int c = 0; c < 7; ++c) *(unsigned long long*)&rowp[36 + 4*c] = 0ull;
            }
        }
    }

    // ---- 4 GAT layers, no barriers ----
    gat_layer<1>(lane, sw, esb, edb, Ap, ws, 0, b1);
    gat_layer<2>(lane, sw, esb, edb, Ap, ws, 1, b2);
    gat_layer<2>(lane, sw, esb, edb, Ap, ws, 2, b3);
    gat_layer<2>(lane, sw, esb, edb, Ap, ws, 3, b4);

    // ---- mean pool (hi+lo) + FC(64->2) + softmax, per wave ----
    {
        float acc = 0.f;
#pragma unroll
        for (int n = 0; n < 32; ++n)
            acc += u2f(((unsigned)sw[n*72 + lane]) << 16)
                 + u2f(((unsigned)sw[2304 + n*72 + lane]) << 16);
        const float p = acc*(1.f/32.f);
        float c0 = p*__ldg(fcW + 2*lane);
        float c1 = p*__ldg(fcW + 2*lane + 1);
#pragma unroll
        for (int off = 32; off > 0; off >>= 1){
            c0 += __shfl_down(c0, off);
            c1 += __shfl_down(c1, off);
        }
        if (lane == 0){
            const float l0 = c0 + __ldg(fcb), l1 = c1 + __ldg(fcb + 1);
            const float m = fmaxf(l0, l1);
            const float e0 = __expf(l0 - m), e1 = __expf(l1 - m);
            const float inv = 1.f/(e0 + e1);
            out[2*g] = l0;
            out[2*g + 1] = l1;
            out[2*NGRAPH + 2*g] = e0*inv;
            out[2*NGRAPH + 2*g + 1] = e1*inv;
        }
    }
}

// prep: split-bf16 W^T planes, shared esed tiles, and QKV^T planes into d_ws.
__global__ void prep(
    const float* __restrict__ W1, const float* __restrict__ W2,
    const float* __restrict__ W3, const float* __restrict__ W4,
    const float* __restrict__ a1s, const float* __restrict__ a1d,
    const float* __restrict__ a2s, const float* __restrict__ a2d,
    const float* __restrict__ a3s, const float* __restrict__ a3d,
    const float* __restrict__ a4s, const float* __restrict__ a4d,
    const float* __restrict__ Wq, const float* __restrict__ Wk,
    const float* __restrict__ Wv,
    char* __restrict__ ws)
{
    const int b = blockIdx.x, tid = threadIdx.x;
    const float* Wl[4] = {W1, W2, W3, W4};
    const int Kl[4] = {10, 64, 64, 64};
    if (b < 32){
        const int l = b >> 3;
        const float* W = Wl[l];
        const int K = Kl[l];
        unsigned short* hi = (unsigned short*)(ws + l*16384);
        unsigned short* lo = hi + 4096;
        const int base = (b & 7)*512;
        for (int idx = base + tid; idx < base + 512; idx += NT){
            const int n = idx >> 6, k = idx & 63;
            const float v = (k < K) ? __ldg(W + k*64 + n) : 0.f;
            const unsigned u = f2u(v);
            const float lof = v - u2f(u & 0xffff0000u);
            hi[idx] = (unsigned short)(u >> 16);
            lo[idx] = (unsigned short)(f2u(lof) >> 16);
        }
    } else if (b < 36){
        const int l = b - 32;
        const float* W = Wl[l];
        const int K = Kl[l];
        const float* asp[4] = {a1s, a2s, a3s, a4s};
        const float* adp[4] = {a1d, a2d, a3d, a4d};
        const int C = (l < 3) ? 16 : 64;
        unsigned short* basep = (unsigned short*)(ws + 65536 + l*4096);
        for (int idx = tid; idx < 1024; idx += NT){
            const int n = idx >> 6, k = idx & 63;   // row n: 2h=was'_h, 2h+1=wad'_h
            float val = 0.f;
            if (n < 8 && k < K){
                const int hh = (l < 3) ? (n >> 1) : 0;
                const float* av = (n & 1) ? adp[l] : asp[l];
                float s = 0.f;
                for (int c = 0; c < C; ++c)
                    s += __ldg(W + k*64 + hh*C + c) * __ldg(av + hh*C + c);
                val = s * LOG2E;
            }
            const unsigned u = f2u(val);
            const float lof = val - u2f(u & 0xffff0000u);
            basep[idx]        = (unsigned short)(u >> 16);
            basep[1024 + idx] = (unsigned short)(f2u(lof) >> 16);
        }
    } else {
        const int mat = b - 36;
        const float* W = (mat == 0) ? Wq : ((mat == 1) ? Wk : Wv);
        unsigned short* hi = (unsigned short*)(ws + 81920 + mat*4096);
        unsigned short* lo = hi + 1024;
        for (int idx = tid; idx < 1024; idx += NT){
            const int i = idx >> 5, m = idx & 31;
            const float v = __ldg(W + m*32 + i);
            const unsigned u = f2u(v);
            const float lof = v - u2f(u & 0xffff0000u);
            hi[idx] = (unsigned short)(u >> 16);
            lo[idx] = (unsigned short)(f2u(lof) >> 16);
        }
    }
}

extern "C" void kernel_launch(void* const* d_in, const int* in_sizes, int n_in,
                              void* d_out, int out_size, void* d_ws, size_t ws_size,
                              hipStream_t stream) {
    (void)in_sizes; (void)n_in; (void)ws_size; (void)out_size;
    prep<<<39, NT, 0, stream>>>(
        (const float*)d_in[6], (const float*)d_in[10], (const float*)d_in[14], (const float*)d_in[18],
        (const float*)d_in[7], (const float*)d_in[8],
        (const float*)d_in[11], (const float*)d_in[12],
        (const float*)d_in[15], (const float*)d_in[16],
        (const float*)d_in[19], (const float*)d_in[20],
        (const float*)d_in[3], (const float*)d_in[4], (const float*)d_in[5],
        (char*)d_ws);
    gnn_fused<<<NGRAPH / GPB, NT, 0, stream>>>(
        (const float*)d_in[0], (const int*)d_in[1],
        (const float*)d_in[9], (const float*)d_in[13], (const float*)d_in[17], (const float*)d_in[21],
        (const float*)d_in[22], (const float*)d_in[23],
        (const char*)d_ws, (float*)d_out);
}